// Round 2
// baseline (417.095 us; speedup 1.0000x reference)
//
#include <hip/hip_runtime.h>

// B=16, S=4096, V=1024, fp32.
// Restructured: never materialize K/V.
//   q[b,o]   = pool[b]·Wq[o,:] + bq[o]
//   qks[b,v] = (1/64) * sum_o q[b,o] Wk[o,v];  c[b] = (1/64) q[b]·bk
//   a[b,s]   = qks[b]·bert[b,s] + c[b]
//   u[b,v]   = sum_s a[b,s] bert[b,s,v];  A[b] = sum_s a[b,s]
//   out[b,d] = Wv[d,:]·u[b] + bv[d]*A[b]

#define BB 16
#define SS 4096
#define VV 1024
#define V4 256   // VV/4

__device__ __forceinline__ float dot4(const float4& a, const float4& b) {
    return a.x*b.x + a.y*b.y + a.z*b.z + a.w*b.w;
}

__device__ __forceinline__ void axpy4(float a, const float4& x, float4& y) {
    y.x = fmaf(a, x.x, y.x); y.y = fmaf(a, x.y, y.y);
    y.z = fmaf(a, x.z, y.z); y.w = fmaf(a, x.w, y.w);
}

__device__ __forceinline__ float wave_allreduce(float v) {
#pragma unroll
    for (int off = 32; off > 0; off >>= 1)
        v += __shfl_xor(v, off, 64);
    return v;
}

// Y[b,o] = X[b,:]·W[o,:] + bias term.  X (16x1024 = 64 KB) staged in LDS once
// per block; each weight row read exactly once chip-wide (4 MB total).
// Grid 256 blocks x 256 thr; wave w handles o = blockIdx*4 + w.
// OUT_MODE=0: Y = X@W^T + bias[o]          (q projection)
// OUT_MODE=1: Y = X@W^T + bias[o]*scale[b] (output projection, scale = A)
template <int OUT_MODE>
__global__ __launch_bounds__(256) void k_xw(const float* __restrict__ X,
                                            const float* __restrict__ W,
                                            const float* __restrict__ bias,
                                            const float* __restrict__ scale,
                                            float* __restrict__ Y) {
    __shared__ float4 Xls[BB * V4];   // 64 KB
    const float4* X4 = (const float4*)X;
    for (int i = threadIdx.x; i < BB * V4; i += 256) Xls[i] = X4[i];
    __syncthreads();

    int w = threadIdx.x >> 6, lane = threadIdx.x & 63;
    int o = blockIdx.x * 4 + w;
    const float4* w4 = (const float4*)W + (size_t)o * V4;
    float4 wv0 = w4[lane], wv1 = w4[64 + lane], wv2 = w4[128 + lane], wv3 = w4[192 + lane];

    float acc[BB];
#pragma unroll
    for (int b = 0; b < BB; ++b) {
        const float4* xb = &Xls[b * V4];
        acc[b] = dot4(wv0, xb[lane]) + dot4(wv1, xb[64 + lane])
               + dot4(wv2, xb[128 + lane]) + dot4(wv3, xb[192 + lane]);
    }
#pragma unroll
    for (int b = 0; b < BB; ++b) acc[b] = wave_allreduce(acc[b]);
    if (lane < BB) {
        int b = lane;
        float bias_t = OUT_MODE ? bias[o] * scale[b] : bias[o];
        Y[b * VV + o] = acc[b] + bias_t;
    }
}

// qks[b,v] = (1/64) * sum_o q[b,o] Wk[o,v]  (atomic combine over o-chunks);
// vc==0 blocks also produce c[b] = (1/64) q[b]·bk partials.
__global__ __launch_bounds__(256) void k_qk(const float* __restrict__ q,
                                            const float* __restrict__ Wk,
                                            const float* __restrict__ bk,
                                            float* __restrict__ qks,
                                            float* __restrict__ c) {
    __shared__ float qs[BB][64];
    int vc = blockIdx.x & 3, dc = blockIdx.x >> 2;
    int dlo = dc * 64;
    for (int i = threadIdx.x; i < BB * 64; i += 256) {
        int b = i >> 6, dd = i & 63;
        qs[b][dd] = q[b * VV + dlo + dd];
    }
    __syncthreads();
    int v = (vc << 8) + threadIdx.x;
    float acc[BB];
#pragma unroll
    for (int b = 0; b < BB; ++b) acc[b] = 0.f;
    for (int dd = 0; dd < 64; ++dd) {
        float wk = Wk[(size_t)(dlo + dd) * VV + v];
#pragma unroll
        for (int b = 0; b < BB; ++b) acc[b] = fmaf(qs[b][dd], wk, acc[b]);
    }
#pragma unroll
    for (int b = 0; b < BB; ++b)
        atomicAdd(&qks[b * VV + v], acc[b] * 0.015625f);

    if (vc == 0 && threadIdx.x < 64) {
        int lane = threadIdx.x;
        float bkv = bk[dlo + lane];
#pragma unroll
        for (int b = 0; b < BB; ++b) {
            float r = wave_allreduce(qs[b][lane] * bkv);
            if (lane == 0) atomicAdd(&c[b], r * 0.015625f);
        }
    }
}

// Fused attention pass: single read of bert (256 MB). Each wave owns 16
// consecutive s rows: a = qks·row + c (butterfly reduce), u += a*row in
// registers. 8-wave LDS combine, one atomic per element per block.
// 512 blocks x 512 thr -> 16 waves/CU for latency hiding.
__global__ __launch_bounds__(512) void k_main(const float* __restrict__ bert,
                                              const float* __restrict__ qks,
                                              const float* __restrict__ c,
                                              float* __restrict__ u,
                                              float* __restrict__ A) {
    int w = threadIdx.x >> 6, lane = threadIdx.x & 63;
    int b = blockIdx.x >> 5, sc = blockIdx.x & 31;   // 32 blocks per batch
    int s0 = sc * 128 + w * 16;                      // 16 s per wave
    const float4* qk4 = (const float4*)qks + b * V4;
    float4 k0 = qk4[lane], k1 = qk4[64 + lane], k2 = qk4[128 + lane], k3 = qk4[192 + lane];
    float cb = c[b];
    float4 u0 = {0,0,0,0}, u1 = {0,0,0,0}, u2 = {0,0,0,0}, u3 = {0,0,0,0};
    float asum = 0.f;
    const float4* base = (const float4*)bert + ((size_t)b * SS + s0) * V4;
#pragma unroll 4
    for (int s = 0; s < 16; ++s) {
        const float4* row = base + (size_t)s * V4;
        float4 x0 = row[lane], x1 = row[64 + lane], x2 = row[128 + lane], x3 = row[192 + lane];
        float p = dot4(k0, x0) + dot4(k1, x1) + dot4(k2, x2) + dot4(k3, x3);
        p = wave_allreduce(p);               // all lanes hold full sum
        float a = p + cb;
        axpy4(a, x0, u0); axpy4(a, x1, u1); axpy4(a, x2, u2); axpy4(a, x3, u3);
        asum += a;
    }
    // combine 8 waves in LDS, then one atomic per element per block
    __shared__ float4 uls[8][256];
    __shared__ float as_[8];
    uls[w][lane]       = u0;
    uls[w][64 + lane]  = u1;
    uls[w][128 + lane] = u2;
    uls[w][192 + lane] = u3;
    if (lane == 0) as_[w] = asum;
    __syncthreads();
    int t = threadIdx.x;
    if (t < 256) {
        float4 s0v = uls[0][t], s1 = uls[1][t], s2 = uls[2][t], s3 = uls[3][t];
        float4 s4 = uls[4][t], s5 = uls[5][t], s6 = uls[6][t], s7 = uls[7][t];
        float* up = u + (size_t)b * VV + 4 * t;
        atomicAdd(up + 0, s0v.x + s1.x + s2.x + s3.x + s4.x + s5.x + s6.x + s7.x);
        atomicAdd(up + 1, s0v.y + s1.y + s2.y + s3.y + s4.y + s5.y + s6.y + s7.y);
        atomicAdd(up + 2, s0v.z + s1.z + s2.z + s3.z + s4.z + s5.z + s6.z + s7.z);
        atomicAdd(up + 3, s0v.w + s1.w + s2.w + s3.w + s4.w + s5.w + s6.w + s7.w);
        if (t == 0)
            atomicAdd(&A[b], as_[0] + as_[1] + as_[2] + as_[3] + as_[4] + as_[5] + as_[6] + as_[7]);
    }
}

extern "C" void kernel_launch(void* const* d_in, const int* in_sizes, int n_in,
                              void* d_out, int out_size, void* d_ws, size_t ws_size,
                              hipStream_t stream) {
    const float* pool = (const float*)d_in[0];
    const float* bert = (const float*)d_in[1];
    const float* Wq   = (const float*)d_in[2];
    const float* bq   = (const float*)d_in[3];
    const float* Wk   = (const float*)d_in[4];
    const float* bk   = (const float*)d_in[5];
    const float* Wv   = (const float*)d_in[6];
    const float* bv   = (const float*)d_in[7];
    float* out = (float*)d_out;

    float* ws  = (float*)d_ws;
    float* q   = ws;            // 16384 floats
    float* qks = ws + 16384;    // 16384 floats (zeroed)
    float* u   = ws + 32768;    // 16384 floats (zeroed)
    float* A   = ws + 49152;    // 16 floats   (zeroed)
    float* c   = ws + 49168;    // 16 floats   (zeroed)

    hipMemsetAsync(qks, 0, (16384 + 16384 + 32) * sizeof(float), stream);
    k_xw<0><<<256, 256, 0, stream>>>(pool, Wq, bq, nullptr, q);
    k_qk   <<<64,  256, 0, stream>>>(q, Wk, bk, qks, c);
    k_main <<<512, 512, 0, stream>>>(bert, qks, c, u, A);
    k_xw<1><<<256, 256, 0, stream>>>(u, Wv, bv, A, out);
}

// Round 4
// 394.158 us; speedup vs baseline: 1.0582x; 1.0582x over previous
//
#include <hip/hip_runtime.h>

// B=16, S=4096, V=1024, fp32.
// Restructured: never materialize K/V.
//   q[b,o]   = pool[b]·Wq[o,:] + bq[o]
//   qks[b,v] = (1/64) * sum_o q[b,o] Wk[o,v];  c[b] = (1/64) q[b]·bk
//   a[b,s]   = qks[b]·bert[b,s] + c[b]
//   u[b,v]   = sum_s a[b,s] bert[b,s,v];  A[b] = sum_s a[b,s]
//   out[b,d] = Wv[d,:]·u[b] + bv[d]*A[b]
//
// Workspace layout (floats):
//   q   [0      : 16384)
//   qks [16384  : 32768)   zeroed by k_xw<0>   (contiguous with c)
//   c   [32768  : 32784)   zeroed by k_xw<0>
//   u   [32784  : 49168)   zeroed by k_qk      (contiguous with A)
//   A   [49168  : 49184)   zeroed by k_qk

#define BB 16
#define SS 4096
#define VV 1024
#define V4 256   // VV/4

// native clang vector type — required by __builtin_nontemporal_load
typedef float vf4 __attribute__((ext_vector_type(4)));

__device__ __forceinline__ float dot4(const vf4& a, const vf4& b) {
    return a.x*b.x + a.y*b.y + a.z*b.z + a.w*b.w;
}

__device__ __forceinline__ void axpy4(float a, const vf4& x, vf4& y) {
    y.x = fmaf(a, x.x, y.x); y.y = fmaf(a, x.y, y.y);
    y.z = fmaf(a, x.z, y.z); y.w = fmaf(a, x.w, y.w);
}

__device__ __forceinline__ float wave_allreduce(float v) {
#pragma unroll
    for (int off = 32; off > 0; off >>= 1)
        v += __shfl_xor(v, off, 64);
    return v;
}

// Y[b,o] = X[b,:]·W[o,:] + bias term.  X (16x1024 = 64 KB) staged in LDS once
// per block; each weight row read exactly once chip-wide (4 MB total).
// Grid 256 blocks x 256 thr; wave w handles o = blockIdx*4 + w.
// OUT_MODE=0: Y = X@W^T + bias[o]; also zeroes zbuf (qks+c, 16400 floats).
// OUT_MODE=1: Y = X@W^T + bias[o]*scale[b] (output projection, scale = A)
template <int OUT_MODE>
__global__ __launch_bounds__(256) void k_xw(const float* __restrict__ X,
                                            const float* __restrict__ W,
                                            const float* __restrict__ bias,
                                            const float* __restrict__ scale,
                                            float* __restrict__ Y,
                                            float* __restrict__ zbuf) {
    if (OUT_MODE == 0) {
        // 256 blocks x 65 floats covers 16400
        int zi = blockIdx.x * 65 + threadIdx.x;
        if (threadIdx.x < 65 && zi < 16400) zbuf[zi] = 0.f;
    }
    __shared__ vf4 Xls[BB * V4];   // 64 KB
    const vf4* X4 = (const vf4*)X;
    for (int i = threadIdx.x; i < BB * V4; i += 256) Xls[i] = X4[i];
    __syncthreads();

    int w = threadIdx.x >> 6, lane = threadIdx.x & 63;
    int o = blockIdx.x * 4 + w;
    const vf4* w4 = (const vf4*)W + (size_t)o * V4;
    vf4 wv0 = w4[lane], wv1 = w4[64 + lane], wv2 = w4[128 + lane], wv3 = w4[192 + lane];

    float acc[BB];
#pragma unroll
    for (int b = 0; b < BB; ++b) {
        const vf4* xb = &Xls[b * V4];
        acc[b] = dot4(wv0, xb[lane]) + dot4(wv1, xb[64 + lane])
               + dot4(wv2, xb[128 + lane]) + dot4(wv3, xb[192 + lane]);
    }
#pragma unroll
    for (int b = 0; b < BB; ++b) acc[b] = wave_allreduce(acc[b]);
    if (lane < BB) {
        int b = lane;
        float bias_t = OUT_MODE ? bias[o] * scale[b] : bias[o];
        Y[b * VV + o] = acc[b] + bias_t;
    }
}

// qks[b,v] = (1/64) * sum_o q[b,o] Wk[o,v]  (atomic combine over o-chunks);
// vc==0 blocks also produce c[b] = (1/64) q[b]·bk partials.
// Also zeroes zbuf (u+A, 16400 floats) for k_main.
__global__ __launch_bounds__(256) void k_qk(const float* __restrict__ q,
                                            const float* __restrict__ Wk,
                                            const float* __restrict__ bk,
                                            float* __restrict__ qks,
                                            float* __restrict__ c,
                                            float* __restrict__ zbuf) {
    {
        int gtid = blockIdx.x * 256 + threadIdx.x;   // 64*256 = 16384 threads
        for (int i = gtid; i < 16400; i += 16384) zbuf[i] = 0.f;
    }
    __shared__ float qs[BB][64];
    int vc = blockIdx.x & 3, dc = blockIdx.x >> 2;
    int dlo = dc * 64;
    for (int i = threadIdx.x; i < BB * 64; i += 256) {
        int b = i >> 6, dd = i & 63;
        qs[b][dd] = q[b * VV + dlo + dd];
    }
    __syncthreads();
    int v = (vc << 8) + threadIdx.x;
    float acc[BB];
#pragma unroll
    for (int b = 0; b < BB; ++b) acc[b] = 0.f;
    for (int dd = 0; dd < 64; ++dd) {
        float wk = Wk[(size_t)(dlo + dd) * VV + v];
#pragma unroll
        for (int b = 0; b < BB; ++b) acc[b] = fmaf(qs[b][dd], wk, acc[b]);
    }
#pragma unroll
    for (int b = 0; b < BB; ++b)
        atomicAdd(&qks[b * VV + v], acc[b] * 0.015625f);

    if (vc == 0 && threadIdx.x < 64) {
        int lane = threadIdx.x;
        float bkv = bk[dlo + lane];
#pragma unroll
        for (int b = 0; b < BB; ++b) {
            float r = wave_allreduce(qs[b][lane] * bkv);
            if (lane == 0) atomicAdd(&c[b], r * 0.015625f);
        }
    }
}

// Fused attention pass: single read of bert (256 MB), non-temporal (no reuse).
// Each wave owns 16 consecutive s rows: a = qks·row + c (butterfly reduce),
// u += a*row in registers. 4-wave LDS combine, one atomic per elem per block.
// 1024 blocks x 256 thr.
__global__ __launch_bounds__(256) void k_main(const float* __restrict__ bert,
                                              const float* __restrict__ qks,
                                              const float* __restrict__ c,
                                              float* __restrict__ u,
                                              float* __restrict__ A) {
    int w = threadIdx.x >> 6, lane = threadIdx.x & 63;
    int b = blockIdx.x >> 6, sc = blockIdx.x & 63;   // 64 blocks per batch
    int s0 = sc * 64 + w * 16;                       // 16 s per wave
    const vf4* qk4 = (const vf4*)qks + b * V4;
    vf4 k0 = qk4[lane], k1 = qk4[64 + lane], k2 = qk4[128 + lane], k3 = qk4[192 + lane];
    float cb = c[b];
    vf4 u0 = {0,0,0,0}, u1 = {0,0,0,0}, u2 = {0,0,0,0}, u3 = {0,0,0,0};
    float asum = 0.f;
    const vf4* base = (const vf4*)bert + ((size_t)b * SS + s0) * V4;
#pragma unroll 4
    for (int s = 0; s < 16; ++s) {
        const vf4* row = base + (size_t)s * V4;
        vf4 x0 = __builtin_nontemporal_load(row + lane);
        vf4 x1 = __builtin_nontemporal_load(row + 64 + lane);
        vf4 x2 = __builtin_nontemporal_load(row + 128 + lane);
        vf4 x3 = __builtin_nontemporal_load(row + 192 + lane);
        float p = dot4(k0, x0) + dot4(k1, x1) + dot4(k2, x2) + dot4(k3, x3);
        p = wave_allreduce(p);               // all lanes hold full sum
        float a = p + cb;
        axpy4(a, x0, u0); axpy4(a, x1, u1); axpy4(a, x2, u2); axpy4(a, x3, u3);
        asum += a;
    }
    // combine 4 waves in LDS, then one atomic per element per block
    __shared__ vf4 uls[4][256];
    __shared__ float as_[4];
    uls[w][lane]       = u0;
    uls[w][64 + lane]  = u1;
    uls[w][128 + lane] = u2;
    uls[w][192 + lane] = u3;
    if (lane == 0) as_[w] = asum;
    __syncthreads();
    int t = threadIdx.x;
    vf4 a0 = uls[0][t], a1 = uls[1][t], a2 = uls[2][t], a3 = uls[3][t];
    float* up = u + (size_t)b * VV + 4 * t;
    atomicAdd(up + 0, a0.x + a1.x + a2.x + a3.x);
    atomicAdd(up + 1, a0.y + a1.y + a2.y + a3.y);
    atomicAdd(up + 2, a0.z + a1.z + a2.z + a3.z);
    atomicAdd(up + 3, a0.w + a1.w + a2.w + a3.w);
    if (t == 0) atomicAdd(&A[b], as_[0] + as_[1] + as_[2] + as_[3]);
}

extern "C" void kernel_launch(void* const* d_in, const int* in_sizes, int n_in,
                              void* d_out, int out_size, void* d_ws, size_t ws_size,
                              hipStream_t stream) {
    const float* pool = (const float*)d_in[0];
    const float* bert = (const float*)d_in[1];
    const float* Wq   = (const float*)d_in[2];
    const float* bq   = (const float*)d_in[3];
    const float* Wk   = (const float*)d_in[4];
    const float* bk   = (const float*)d_in[5];
    const float* Wv   = (const float*)d_in[6];
    const float* bv   = (const float*)d_in[7];
    float* out = (float*)d_out;

    float* ws  = (float*)d_ws;
    float* q   = ws;            // 16384 floats
    float* qks = ws + 16384;    // 16384 floats (zeroed by k_xw<0>)
    float* c   = ws + 32768;    // 16 floats    (zeroed by k_xw<0>)
    float* u   = ws + 32784;    // 16384 floats (zeroed by k_qk)
    float* A   = ws + 49168;    // 16 floats    (zeroed by k_qk)

    k_xw<0><<<256,  256, 0, stream>>>(pool, Wq, bq, nullptr, q, qks);
    k_qk   <<<64,   256, 0, stream>>>(q, Wk, bk, qks, c, u);
    k_main <<<1024, 256, 0, stream>>>(bert, qks, c, u, A);
    k_xw<1><<<256,  256, 0, stream>>>(u, Wv, bv, A, out, nullptr);
}